// Round 1
// baseline (139.269 us; speedup 1.0000x reference)
//
#include <hip/hip_runtime.h>
#include <math.h>

#define N_E   32
#define NUP   16
#define N_I   128
#define H_S   512
#define F_LEN 1544      // 3*512 + 2*4
#define N_K   16
#define CH    16
#define CHUNK 97        // ceil(1544/16); last chunk = 89

// workspace layout (float offsets)
#define WS_SH    0                      // [32][512]
#define WS_DH    16384                  // [32][32][4]
#define WS_ENN   20480                  // [32][128] eN_norm
#define WS_PART  24576                  // [32][16][512] matvec partials
#define WS_PHI   286720                 // [16][32][32]
#define WS_DETS  303104                 // [32] (k*2 + {up,dn})

// ---------------------------------------------------------------------------
// Init: eN, eN_norm, sh0, dh0
__global__ void k_init(const float* __restrict__ ep, const float* __restrict__ nuc,
                       float* __restrict__ ws) {
    float* sh  = ws + WS_SH;
    float* dh  = ws + WS_DH;
    float* eNn = ws + WS_ENN;
    int t = threadIdx.x;
    for (int idx = t; idx < N_E * N_I; idx += 256) {
        int j = idx >> 7, m = idx & 127;
        float dx = ep[j*3+0] - nuc[m*3+0];
        float dy = ep[j*3+1] - nuc[m*3+1];
        float dz = ep[j*3+2] - nuc[m*3+2];
        float nr = sqrtf(dx*dx + dy*dy + dz*dz);
        eNn[j*N_I + m] = nr;
        sh[j*H_S + 3*m + 0] = dx;
        sh[j*H_S + 3*m + 1] = dy;
        sh[j*H_S + 3*m + 2] = dz;
        sh[j*H_S + 384 + m] = nr;
    }
    for (int idx = t; idx < N_E * N_E; idx += 256) {
        int a = idx >> 5, b = idx & 31;
        float dx = ep[a*3+0] - ep[b*3+0];
        float dy = ep[a*3+1] - ep[b*3+1];
        float dz = ep[a*3+2] - ep[b*3+2];
        float nr = sqrtf(dx*dx + dy*dy + dz*dz);
        float* d = dh + (a*N_E + b)*4;
        d[0] = dx; d[1] = dy; d[2] = dz; d[3] = nr;
    }
}

// ---------------------------------------------------------------------------
// Streaming matvec: block (n, ch) computes partial[n][ch][o] = sum_{f in chunk} V[li,n,f,o]*fvec[n,f]
// fvec values (incl. g_up/g_dn/dg means) built on the fly into LDS.
__global__ __launch_bounds__(256) void k_matvec(const float* __restrict__ V,
                                                const float* __restrict__ ws,
                                                float* __restrict__ partial, int li) {
    const float* sh = ws + WS_SH;
    const float* dh = ws + WS_DH;
    __shared__ float fv[CHUNK];
    int n = blockIdx.x, ch = blockIdx.y, t = threadIdx.x;
    int f0 = ch * CHUNK;
    int flen = F_LEN - f0; if (flen > CHUNK) flen = CHUNK;

    if (t < flen) {
        int fi = f0 + t;
        float v;
        if (fi < 512) {
            v = sh[n*H_S + fi];
        } else if (fi < 1024) {
            float s = 0.f; int o = fi - 512;
            #pragma unroll
            for (int m = 0; m < 16; ++m) s += sh[m*H_S + o];
            v = s * 0.0625f;
        } else if (fi < 1536) {
            float s = 0.f; int o = fi - 1024;
            #pragma unroll
            for (int m = 16; m < 32; ++m) s += sh[m*H_S + o];
            v = s * 0.0625f;
        } else if (fi < 1540) {
            int i = fi - 1536; float s = 0.f;
            #pragma unroll
            for (int j = 0; j < 16; ++j) s += dh[(n*N_E + j)*4 + i];
            v = s * 0.0625f;
        } else {
            int i = fi - 1540; float s = 0.f;
            #pragma unroll
            for (int j = 16; j < 32; ++j) s += dh[(n*N_E + j)*4 + i];
            v = s * 0.0625f;
        }
        fv[t] = v;
    }
    __syncthreads();

    const float2* Vp = reinterpret_cast<const float2*>(
        V + ((size_t)(li*N_E + n)*F_LEN + f0)*H_S) + t;
    float ax = 0.f, ay = 0.f;
    if (flen == CHUNK) {
        #pragma unroll 8
        for (int r = 0; r < CHUNK; ++r) {
            float2 w = Vp[(size_t)r * 256];
            float fr = fv[r];
            ax = fmaf(w.x, fr, ax);
            ay = fmaf(w.y, fr, ay);
        }
    } else {
        #pragma unroll 8
        for (int r = 0; r < 89; ++r) {   // tail chunk is exactly 89 rows
            float2 w = Vp[(size_t)r * 256];
            float fr = fv[r];
            ax = fmaf(w.x, fr, ax);
            ay = fmaf(w.y, fr, ay);
        }
    }
    float2* pp = reinterpret_cast<float2*>(partial + ((size_t)n*CH + ch)*H_S) + t;
    *pp = make_float2(ax, ay);
}

// ---------------------------------------------------------------------------
// Reduce partials -> sh (tanh + bias + residual, in place); also the tiny dh update.
__global__ __launch_bounds__(512) void k_reduce(const float* __restrict__ partial,
                                                const float* __restrict__ bv,
                                                const float* __restrict__ Wm,
                                                const float* __restrict__ cv,
                                                float* __restrict__ ws, int li) {
    float* sh = ws + WS_SH;
    float* dh = ws + WS_DH;
    int n = blockIdx.x, t = threadIdx.x;
    float s = 0.f;
    #pragma unroll
    for (int ch = 0; ch < CH; ++ch) s += partial[((size_t)n*CH + ch)*H_S + t];
    float ns = tanhf(s + bv[((size_t)li*N_E + n)*H_S + t]) + sh[n*H_S + t];

    float dval = 0.f; int j2 = 0, ii = 0;
    if (t < 128) {
        j2 = t >> 2; ii = t & 3;
        const float* Wp = Wm + ((((size_t)li*N_E + n)*N_E + j2)*4 + ii)*4;
        const float* dr = dh + (n*N_E + j2)*4;
        float acc = Wp[0]*dr[0] + Wp[1]*dr[1] + Wp[2]*dr[2] + Wp[3]*dr[3];
        dval = tanhf(acc + cv[(((size_t)li*N_E + n)*N_E + j2)*4 + ii]) + dr[ii];
    }
    __syncthreads();
    sh[n*H_S + t] = ns;
    if (t < 128) dh[(n*N_E + j2)*4 + ii] = dval;
}

// ---------------------------------------------------------------------------
// phi[k,i,j] = (fw[k,i].sh[j] + fb[k,i]) * sum_m pi[k,i,m]*exp(-|sig[k,i,m]|*eNn[j,m])
// One wave per (k,i).
__global__ __launch_bounds__(64) void k_env(const float* __restrict__ fw,
                                            const float* __restrict__ fb,
                                            const float* __restrict__ pw,
                                            const float* __restrict__ sw,
                                            const float* __restrict__ ws,
                                            float* __restrict__ phi) {
    const float* sh  = ws + WS_SH;
    const float* eNn = ws + WS_ENN;
    int ki = blockIdx.x;            // k*32 + i
    int t  = threadIdx.x;           // 0..63
    __shared__ float wloc[H_S];
    for (int c = t; c < H_S; c += 64) wloc[c] = fw[(size_t)ki*H_S + c];
    float p0 = pw[ki*N_I + t],            p1 = pw[ki*N_I + 64 + t];
    float s0 = fabsf(sw[ki*N_I + t]),     s1 = fabsf(sw[ki*N_I + 64 + t]);
    float fbv = fb[ki];
    __syncthreads();
    for (int j = 0; j < N_E; ++j) {
        float fd = 0.f;
        #pragma unroll
        for (int q = 0; q < 8; ++q)
            fd = fmaf(wloc[t*8 + q], sh[j*H_S + t*8 + q], fd);
        float env = p0 * expf(-s0 * eNn[j*N_I + t]) + p1 * expf(-s1 * eNn[j*N_I + 64 + t]);
        #pragma unroll
        for (int off = 32; off; off >>= 1) {
            fd  += __shfl_down(fd, off);
            env += __shfl_down(env, off);
        }
        if (t == 0) phi[(size_t)ki*N_E + j] = (fd + fbv) * env;
    }
}

// ---------------------------------------------------------------------------
// 16x16 determinant per block via row-per-lane Gaussian elimination w/ partial pivoting.
// block b: k = b>>1, spin = b&1 (0: rows/cols 0..15, 1: rows/cols 16..31)
__global__ __launch_bounds__(64) void k_det(const float* __restrict__ ws_phi,
                                            float* __restrict__ dets) {
    int b = blockIdx.x, k = b >> 1, sp = b & 1;
    int lane = threadIdx.x;
    int r = lane & 15;
    int base = sp ? 16 : 0;
    float a[16];
    #pragma unroll
    for (int c = 0; c < 16; ++c)
        a[c] = ws_phi[((size_t)k*N_E + base + r)*N_E + base + c];
    bool used = (lane >= 16);
    float prod = 1.f;
    int sigma[16];
    #pragma unroll
    for (int p = 0; p < 16; ++p) {
        float v = used ? -1.f : fabsf(a[p]);
        int idx = lane;
        #pragma unroll
        for (int off = 32; off; off >>= 1) {
            float ov = __shfl_xor(v, off);
            int   oi = __shfl_xor(idx, off);
            if (ov > v || (ov == v && oi < idx)) { v = ov; idx = oi; }
        }
        int q = idx;                       // pivot lane (all lanes agree)
        float pv = __shfl(a[p], q);
        prod *= pv;
        sigma[p] = q;
        float factor = (!used && lane != q && pv != 0.f) ? (a[p] / pv) : 0.f;
        #pragma unroll
        for (int c = p; c < 16; ++c) {
            float pr = __shfl(a[c], q);
            a[c] -= factor * pr;
        }
        if (lane == q) used = true;
    }
    if (lane == 0) {
        int inv = 0;
        #pragma unroll
        for (int x = 0; x < 16; ++x)
            #pragma unroll
            for (int y = x + 1; y < 16; ++y) inv += (sigma[x] > sigma[y]) ? 1 : 0;
        dets[b] = prod * ((inv & 1) ? -1.f : 1.f);
    }
}

// ---------------------------------------------------------------------------
__global__ void k_out(const float* __restrict__ dets, const float* __restrict__ omega,
                      float* __restrict__ out) {
    if (threadIdx.x == 0) {
        float s = 0.f;
        for (int k = 0; k < N_K; ++k)
            s += omega[k] * dets[2*k + 0] * dets[2*k + 1];
        out[0] = s;
    }
}

// ---------------------------------------------------------------------------
extern "C" void kernel_launch(void* const* d_in, const int* in_sizes, int n_in,
                              void* d_out, int out_size, void* d_ws, size_t ws_size,
                              hipStream_t stream) {
    const float* ep  = (const float*)d_in[0];   // [32,3]
    const float* nuc = (const float*)d_in[1];   // [128,3]
    const float* V   = (const float*)d_in[2];   // [4,32,1544,512]
    const float* bv  = (const float*)d_in[3];   // [4,32,512]
    const float* Wm  = (const float*)d_in[4];   // [4,32,32,4,4]
    const float* cv  = (const float*)d_in[5];   // [4,32,32,4]
    const float* fw  = (const float*)d_in[6];   // [16,32,512]
    const float* fb  = (const float*)d_in[7];   // [16,32]
    const float* pw  = (const float*)d_in[8];   // [16,32,128]
    const float* sw  = (const float*)d_in[9];   // [16,32,128]
    const float* om  = (const float*)d_in[10];  // [16]
    float* out = (float*)d_out;
    float* ws  = (float*)d_ws;

    float* partial = ws + WS_PART;
    float* phi     = ws + WS_PHI;
    float* dets    = ws + WS_DETS;

    k_init<<<dim3(1), dim3(256), 0, stream>>>(ep, nuc, ws);

    // layer sequence quirk: 0, 1, 2, then 2 again
    for (int a = 0; a < 4; ++a) {
        int li = (a < 3) ? a : 2;
        k_matvec<<<dim3(N_E, CH), dim3(256), 0, stream>>>(V, ws, partial, li);
        k_reduce<<<dim3(N_E), dim3(512), 0, stream>>>(partial, bv, Wm, cv, ws, li);
    }

    k_env<<<dim3(N_K * N_E), dim3(64), 0, stream>>>(fw, fb, pw, sw, ws, phi);
    k_det<<<dim3(2 * N_K), dim3(64), 0, stream>>>(phi, dets);
    k_out<<<dim3(1), dim3(64), 0, stream>>>(dets, om, out);
}